// Round 3
// baseline (212.795 us; speedup 1.0000x reference)
//
#include <hip/hip_runtime.h>

// Problem constants
#define NB   16
#define CIN  256
#define COUT 256
#define HH   32
#define WW   32
#define HW   1024           // 32*32
#define KK   9
#define CK   2304           // CIN*KK  (ordered k*256 + c, tap-major)

typedef __bf16 bf16x8 __attribute__((ext_vector_type(8)));
typedef float  f32x4  __attribute__((ext_vector_type(4)));

__device__ __forceinline__ unsigned short f2bf(float f) {
    unsigned int u = __float_as_uint(f);
    u += 0x7FFFu + ((u >> 16) & 1u);          // round-nearest-even
    return (unsigned short)(u >> 16);
}
__device__ __forceinline__ float bfhi(unsigned int u) {   // high bf16 -> f32
    return __uint_as_float(u & 0xFFFF0000u);
}
__device__ __forceinline__ float bflo(unsigned int u) {   // low bf16 -> f32
    return __uint_as_float(u << 16);
}

typedef const __attribute__((address_space(1))) void* gas_ptr;
typedef __attribute__((address_space(3))) void* las_ptr;

__device__ __forceinline__ void async16(const void* g, void* l) {
    __builtin_amdgcn_global_load_lds((gas_ptr)g, (las_ptr)l, 16, 0, 0);
}

#define SB() __builtin_amdgcn_sched_barrier(0)
// Raw barrier: LDS-visibility only. vmcnt is deliberately NOT drained —
// A-DMA completion is enforced by vmcnt FIFO order (the lerp's wait on the
// younger corner-gather loads implies the older DMAs are done).
#define SYNC() do { SB(); asm volatile("s_waitcnt lgkmcnt(0)" ::: "memory"); SB(); \
                    __builtin_amdgcn_s_barrier(); SB(); } while (0)

// Monotonic grid-barrier counter. Never reset: each replay's 256 blocks take
// tickets [256k, 256k+256); every block spins until ctr reaches 256(k+1).
__device__ unsigned g_ctr = 0;

// ----------------------------------------------------------------- mono ----
// Single kernel: phase0 prep (weight bf16-conv + x transpose) -> device-wide
// ticket barrier -> phase1 deform-conv GEMM (round-1 structure, BM=256).
// Grid 256 blocks x 512 threads, 112 KB LDS -> exactly 1 block/CU -> all
// blocks co-resident -> spin barrier cannot deadlock.
__global__ __launch_bounds__(512, 2) void mono_kernel(const float* __restrict__ wt,
                                                      const float* __restrict__ x,
                                                      const float* __restrict__ off,
                                                      unsigned short* __restrict__ wbf,
                                                      unsigned short* __restrict__ xtb,
                                                      float* __restrict__ out) {
    __shared__ unsigned short As[3][256 * 64];   // 96 KB (triple buffer / prep scratch)
    __shared__ unsigned short Bs[2][64 * 64];    // 16 KB

    const int tid  = threadIdx.x;
    const int id   = blockIdx.x;

    // ==================== phase 0: prep (scratch = As) ====================
    {
        float* scratch = (float*)&As[0][0];

        // ---- weight conv: this block handles o-row `id`
        const float* wo = wt + (size_t)id * CK;
        for (int i = tid; i < CK; i += 512) scratch[i] = wo[i];
        __syncthreads();
        unsigned short* wdst = wbf + (size_t)id * CK;
        for (int i = tid; i < CK; i += 512) {
            int k = i >> 8, c = i & 255;
            wdst[i] = f2bf(scratch[c * KK + k]);   // bank stride 9: conflict-free
        }
        __syncthreads();

        // ---- x transpose: 4 tiles of 64(c) x 64(hw), two at a time.
        // XCD id&7 preps images {2*xcd, 2*xcd+1} == the images its fused
        // blocks consume (same id&7 decode below) -> tiles stay in this L2.
        const int xcd  = id & 7, jb = id >> 3;      // jb: 0..31
        const int half = tid >> 8, t = tid & 255;   // two 256-thread halves
        float* lt = scratch + half * (64 * 65);
#pragma unroll 1
        for (int it = 0; it < 2; ++it) {
            int idx  = jb * 4 + it * 2 + half;      // 0..127 within XCD
            int n    = (xcd << 1) + (idx >> 6);
            int rest = idx & 63;
            int hw0  = (rest >> 2) << 6;
            int c0   = (rest & 3) << 6;
            {
                int c = t >> 2, q = t & 3;
                const float4* base = (const float4*)(x + ((size_t)(n * CIN + c0 + c)) * HW + hw0 + q * 16);
#pragma unroll
                for (int j2 = 0; j2 < 4; ++j2) {
                    float4 v = base[j2];
                    lt[c * 65 + q * 16 + j2 * 4 + 0] = v.x;
                    lt[c * 65 + q * 16 + j2 * 4 + 1] = v.y;
                    lt[c * 65 + q * 16 + j2 * 4 + 2] = v.z;
                    lt[c * 65 + q * 16 + j2 * 4 + 3] = v.w;
                }
            }
            __syncthreads();
            {
                int hwl = t >> 2, seg = (t & 3) * 16;
                unsigned dw2[8];
#pragma unroll
                for (int j2 = 0; j2 < 8; ++j2) {
                    float f0 = lt[(seg + 2 * j2) * 65 + hwl];
                    float f1 = lt[(seg + 2 * j2 + 1) * 65 + hwl];
                    dw2[j2] = (unsigned)f2bf(f0) | ((unsigned)f2bf(f1) << 16);
                }
                uint4* d2 = (uint4*)(xtb + ((size_t)(n * HW + hw0 + hwl)) * CIN + c0 + seg);
                d2[0] = *(uint4*)&dw2[0];
                d2[1] = *(uint4*)&dw2[4];
            }
            __syncthreads();
        }
    }

    // ==================== phase-1 thread/block decode =====================
    const int wv   = tid >> 6;                // 0..7  (M position, 32 rows each)
    const int lane = tid & 63;
    const int quad = lane >> 4;
    const int l15  = lane & 15;

    const int hw_local = tid >> 3;            // 0..63
    const int seg      = tid & 7;             // 8-channel segment within 64

    const int n   = ((id & 7) << 1) | ((id >> 3) & 1);
    const int hw0 = (id >> 4) * 64;

    const int hw = hw0 + hw_local;
    const int h  = hw >> 5, w = hw & 31;

    const int srow   = lane >> 3;
    const int schunk = (lane & 7) ^ (srow & 7);

    const uint4*  xb4  = (const uint4*)(xtb + (size_t)n * HW * CIN);
    const float2* offp = (const float2*)(off + ((size_t)n * HW + hw) * (2 * KK));

    // offset prefetch issued BEFORE the fence: its latency hides under the
    // vmcnt(0) drain the release fence performs anyway.
    float2 o0 = offp[0];

    // ==================== device-wide ticket barrier ======================
    __threadfence();                          // agent release: drain + L2 wb
    __syncthreads();                          // whole block's stores fenced
    if (tid == 0) {
        unsigned ticket = __hip_atomic_fetch_add(&g_ctr, 1u, __ATOMIC_ACQ_REL,
                                                 __HIP_MEMORY_SCOPE_AGENT);
        unsigned target = ((ticket >> 8) + 1) << 8;
        while (__hip_atomic_load(&g_ctr, __ATOMIC_ACQUIRE,
                                 __HIP_MEMORY_SCOPE_AGENT) < target)
            __builtin_amdgcn_s_sleep(2);
    }
    __syncthreads();
    __threadfence();                          // agent acquire: invalidate L1/L2

    // ==================== phase 1: deform-conv GEMM =======================
    f32x4 acc[2][4] = {};

    auto setup2 = [&](float2 o, int tapv, float* wg, int* ix) {
        float py = (float)(h + tapv / 3 - 1) + o.x;
        float px = (float)(w + tapv % 3 - 1) + o.y;
        float y0f = floorf(py), x0f = floorf(px);
        float ly = py - y0f, lx = px - x0f;
        int y0 = (int)y0f, x0 = (int)x0f;
#pragma unroll
        for (int c2 = 0; c2 < 4; ++c2) {
            int yy = y0 + (c2 >> 1);
            int xx = x0 + (c2 & 1);
            float wy = (c2 >> 1) ? ly : 1.0f - ly;
            float wx = (c2 & 1) ? lx : 1.0f - lx;
            bool v = (yy >= 0) && (yy < HH) && (xx >= 0) && (xx < WW);
            wg[c2] = v ? wy * wx : 0.0f;
            int yc = yy < 0 ? 0 : (yy > HH - 1 ? HH - 1 : yy);
            int xc = xx < 0 ? 0 : (xx > WW - 1 ? WW - 1 : xx);
            ix[c2] = yc * WW + xc;
        }
    };

    auto loadc = [&](uint4 cr[4], const int* ix, int q) {
#pragma unroll
        for (int c2 = 0; c2 < 4; ++c2)
            cr[c2] = xb4[(size_t)ix[c2] * 32 + q * 8 + seg];
    };

    auto dmaA = [&](int ai, int kblk) {
        const unsigned short* wsrc = wbf + (size_t)kblk * 64 + (size_t)srow * CK + schunk * 8;
        unsigned short* dst = &As[ai][0];
#pragma unroll
        for (int j = 0; j < 4; ++j) {
            int rb = wv * 32 + j * 8;
            async16(wsrc + (size_t)rb * CK, dst + rb * 64);
        }
    };

    auto lerpB = [&](int bi, const uint4 cr[4], const float* wg) {
        unsigned u0[4], u1[4], u2[4], u3[4];
        *(uint4*)u0 = cr[0]; *(uint4*)u1 = cr[1];
        *(uint4*)u2 = cr[2]; *(uint4*)u3 = cr[3];
        unsigned dw[4];
#pragma unroll
        for (int d = 0; d < 4; ++d) {
            float lo = wg[0] * bflo(u0[d]) + wg[1] * bflo(u1[d])
                     + wg[2] * bflo(u2[d]) + wg[3] * bflo(u3[d]);
            float hi = wg[0] * bfhi(u0[d]) + wg[1] * bfhi(u1[d])
                     + wg[2] * bfhi(u2[d]) + wg[3] * bfhi(u3[d]);
            dw[d] = (unsigned)f2bf(lo) | ((unsigned)f2bf(hi) << 16);
        }
        *(uint4*)&Bs[bi][hw_local * 64 + (seg ^ (hw_local & 7)) * 8] = *(uint4*)dw;
    };

    auto mfma_step = [&](int ai, int bi) {
        const unsigned short* Ap = &As[ai][0];
        const unsigned short* Bp = &Bs[bi][0];
        bf16x8 af[2][2], bfr[4][2];
#pragma unroll
        for (int mi = 0; mi < 2; ++mi)
#pragma unroll
            for (int hh = 0; hh < 2; ++hh) {
                int row = wv * 32 + mi * 16 + l15;
                int ch  = (hh * 4 + quad) ^ (row & 7);
                af[mi][hh] = *(const bf16x8*)(Ap + row * 64 + ch * 8);
            }
#pragma unroll
        for (int ni = 0; ni < 4; ++ni)
#pragma unroll
            for (int hh = 0; hh < 2; ++hh) {
                int row = ni * 16 + l15;
                int ch  = (hh * 4 + quad) ^ (row & 7);
                bfr[ni][hh] = *(const bf16x8*)(Bp + row * 64 + ch * 8);
            }
        __builtin_amdgcn_s_setprio(1);
#pragma unroll
        for (int mi = 0; mi < 2; ++mi)
#pragma unroll
            for (int ni = 0; ni < 4; ++ni) {
                acc[mi][ni] = __builtin_amdgcn_mfma_f32_16x16x32_bf16(af[mi][0], bfr[ni][0], acc[mi][ni], 0, 0, 0);
                acc[mi][ni] = __builtin_amdgcn_mfma_f32_16x16x32_bf16(af[mi][1], bfr[ni][1], acc[mi][ni], 0, 0, 0);
            }
        __builtin_amdgcn_s_setprio(0);
    };

    // ---- prologue: As[0]<-k0, As[1]<-k1 (DMA), Bs[0]<-lerp(k0), crB holds k1
    float wgc[4], wgn[4];
    int   ixc[4], ixn[4];
    uint4 crA[4], crB[4];
    {
        setup2(o0, 0, wgc, ixc);
        dmaA(0, 0);
        dmaA(1, 1);
        SB();
        loadc(crA, ixc, 0);
        loadc(crB, ixc, 1);
        SB();
        lerpB(0, crA, wgc);   // compiler wait on crA drains both DMAs (FIFO)
        SYNC();
    }

    // ---- main loop: step s = tap*4+q. mfma reads As[s%3], Bs[s%2].
    // DMA at step s targets As[(s+2)%3] with kblock s+2.
    int i0 = 0;                               // == (tap*4) % 3
#pragma unroll 1
    for (int tap = 0; tap < 9; ++tap) {
        const int i1 = (i0 == 2) ? 0 : i0 + 1;
        const int i2 = (i1 == 2) ? 0 : i1 + 1;
        const int kb = tap * 4;
        const bool more = (tap < 8);

        // q0: dma k(kb+2)->As[i2] | lerp k(kb+1)->Bs[1] | loadc k(kb+2) | mfma k(kb)
        dmaA(i2, kb + 2);
        SB();
        lerpB(1, crB, wgc);
        SB();
        loadc(crA, ixc, 2);
        SB();
        mfma_step(i0, 0);
        SYNC();

        // q1: dma k(kb+3)->As[i0] | lerp k(kb+2)->Bs[0] | loadc k(kb+3) | mfma k(kb+1)
        dmaA(i0, kb + 3);
        SB();
        lerpB(0, crA, wgc);
        SB();
        loadc(crB, ixc, 3);
        SB();
        mfma_step(i1, 1);
        SYNC();

        // q2: offp prefetch FIRST (so its wait can't drain the new DMA)
        //     dma k(kb+4)->As[i1] | lerp k(kb+3)->Bs[1] | setup+loadc k(kb+4) | mfma k(kb+2)
        float2 onx = {};
        if (more) onx = offp[tap + 1];
        SB();
        if (more) dmaA(i1, kb + 4);
        SB();
        lerpB(1, crB, wgc);
        SB();
        if (more) { setup2(onx, tap + 1, wgn, ixn); loadc(crA, ixn, 0); }
        SB();
        mfma_step(i2, 0);
        SYNC();

        // q3: dma k(kb+5)->As[i2] | lerp k(kb+4)->Bs[0] (new tap!) | loadc k(kb+5) | mfma k(kb+3)
        if (more) {
            dmaA(i2, kb + 5);
            SB();
            lerpB(0, crA, wgn);
            SB();
            loadc(crB, ixn, 1);
#pragma unroll
            for (int c2 = 0; c2 < 4; ++c2) { wgc[c2] = wgn[c2]; ixc[c2] = ixn[c2]; }
            SB();
            mfma_step(i0, 1);
            SYNC();
        } else {
            mfma_step(i0, 1);        // last step, no barrier needed after
        }
        i0 = i1;
    }

    // ---- epilogue: D layout col = lane&15, row = quad*4 + reg
    float* opnt = out + (size_t)n * COUT * HW + hw0;
#pragma unroll
    for (int mi = 0; mi < 2; ++mi)
#pragma unroll
        for (int ni = 0; ni < 4; ++ni) {
            int col = ni * 16 + l15;
#pragma unroll
            for (int rr = 0; rr < 4; ++rr) {
                int row = wv * 32 + mi * 16 + quad * 4 + rr;
                opnt[(size_t)row * HW + col] = acc[mi][ni][rr];
            }
        }
}

// --------------------------------------------------------------- launch ----
extern "C" void kernel_launch(void* const* d_in, const int* in_sizes, int n_in,
                              void* d_out, int out_size, void* d_ws, size_t ws_size,
                              hipStream_t stream) {
    const float* x   = (const float*)d_in[0];   // [16][256][32][32]
    const float* off = (const float*)d_in[1];   // [16][1024][18]
    const float* wt  = (const float*)d_in[2];   // [256][256][3][3]
    float* out = (float*)d_out;                 // [16][256][32][32]

    unsigned short* wbf = (unsigned short*)d_ws;                        // 1179648 B
    unsigned short* xtb = (unsigned short*)((char*)d_ws + 1179648);     // 8388608 B

    mono_kernel<<<256, 512, 0, stream>>>(wt, x, off, wbf, xtb, out);
}

// Round 4
// 119.472 us; speedup vs baseline: 1.7811x; 1.7811x over previous
//
#include <hip/hip_runtime.h>

// Problem constants
#define NB   16
#define CIN  256
#define COUT 256
#define HH   32
#define WW   32
#define HW   1024           // 32*32
#define KK   9
#define CK   2304           // CIN*KK  (ordered k*256 + c, tap-major)

typedef __bf16 bf16x8 __attribute__((ext_vector_type(8)));
typedef float  f32x4  __attribute__((ext_vector_type(4)));

__device__ __forceinline__ unsigned short f2bf(float f) {
    unsigned int u = __float_as_uint(f);
    u += 0x7FFFu + ((u >> 16) & 1u);          // round-nearest-even
    return (unsigned short)(u >> 16);
}
__device__ __forceinline__ float bfhi(unsigned int u) {   // high bf16 -> f32
    return __uint_as_float(u & 0xFFFF0000u);
}
__device__ __forceinline__ float bflo(unsigned int u) {   // low bf16 -> f32
    return __uint_as_float(u << 16);
}

typedef const __attribute__((address_space(1))) void* gas_ptr;
typedef __attribute__((address_space(3))) void* las_ptr;

__device__ __forceinline__ void async16(const void* g, void* l) {
    __builtin_amdgcn_global_load_lds((gas_ptr)g, (las_ptr)l, 16, 0, 0);
}

#define SB() __builtin_amdgcn_sched_barrier(0)
// Raw barrier: LDS-visibility only. vmcnt is deliberately NOT drained —
// A-DMA completion is enforced by vmcnt FIFO order (the lerp's wait on the
// younger corner-gather loads implies the older DMAs are done).
#define SYNC() do { SB(); asm volatile("s_waitcnt lgkmcnt(0)" ::: "memory"); SB(); \
                    __builtin_amdgcn_s_barrier(); SB(); } while (0)

// ----------------------------------------------------------------- prep ----
// One kernel, two roles (saves a launch and runs them concurrently):
//   blocks [0,256):    weight fp32 [O][C][3][3] -> bf16 [O][k*256+c]
//   blocks [256,1280): x fp32 [n][c][hw] -> xtb bf16 [n][hw][c] (64x64 tiles)
// Measured (round 2): residual incl. both launch gaps ~= 55 us vs 72 us for
// the two-kernel prep. Grid-barrier mono fusion measured WORSE (round 3:
// agent-fence L2 invalidation costs ~100 us of gather-latency) — keep the
// two-dispatch structure.
__global__ __launch_bounds__(256) void prep_kernel(const float* __restrict__ w,
                                                   unsigned short* __restrict__ wbf,
                                                   const float* __restrict__ x,
                                                   unsigned short* __restrict__ xtb) {
    __shared__ float lsbuf[64 * 65];
    const int t = threadIdx.x;

    if (blockIdx.x < 256) {
        // ---- wconv role
        const int o = blockIdx.x;
        const float* wo = w + (size_t)o * CK;
#pragma unroll
        for (int i = t; i < CK; i += 256) lsbuf[i] = wo[i];
        __syncthreads();
        unsigned short* dst = wbf + (size_t)o * CK;
#pragma unroll
        for (int i = t; i < CK; i += 256) {
            int k = i >> 8, c = i & 255;
            dst[i] = f2bf(lsbuf[c * KK + k]);     // bank stride 9: conflict-free
        }
        return;
    }

    // ---- xt role
    float (*ls)[65] = (float(*)[65])lsbuf;
    const int id  = blockIdx.x - 256;
    const int c0  = (id & 3) << 6;
    const int hw0 = ((id >> 2) & 15) << 6;
    const int n   = id >> 6;
    {
        int c = t >> 2, q = t & 3;
        const float4* base = (const float4*)(x + ((size_t)(n * CIN + c0 + c)) * HW + hw0 + q * 16);
#pragma unroll
        for (int j = 0; j < 4; ++j) {
            float4 v = base[j];
            ls[c][q * 16 + j * 4 + 0] = v.x;
            ls[c][q * 16 + j * 4 + 1] = v.y;
            ls[c][q * 16 + j * 4 + 2] = v.z;
            ls[c][q * 16 + j * 4 + 3] = v.w;
        }
    }
    __syncthreads();
    {
        int hw = t >> 2, seg = (t & 3) * 16;
        unsigned int dw[8];
#pragma unroll
        for (int j = 0; j < 8; ++j) {
            float f0 = ls[seg + 2 * j][hw];
            float f1 = ls[seg + 2 * j + 1][hw];
            dw[j] = (unsigned)f2bf(f0) | ((unsigned)f2bf(f1) << 16);
        }
        uint4* dst = (uint4*)(xtb + ((size_t)(n * HW + hw0 + hw)) * CIN + c0 + seg);
        dst[0] = *(uint4*)&dw[0];
        dst[1] = *(uint4*)&dw[4];
    }
}

// ---------------------------------------------------------------- fused ----
// Round-1 structure (measured 50.2 us): BM=256, BN=64, BK=64, 512 thr/8 waves.
// As triple-buffered (DMA 2 steps ahead; completion via vmcnt FIFO order —
// never drained at barriers); Bs double-buffered, lerped one step ahead from
// prefetched corner regs. Raw barrier (lgkmcnt(0)+s_barrier). setprio around
// the MFMA cluster. BM=128 2-block variant measured WORSE (round 2: B-path
// work duplicated per CU, +20 us) — keep BM=256.
__global__ __launch_bounds__(512, 2) void fused_kernel(const unsigned short* __restrict__ wbf,
                                                       const unsigned short* __restrict__ xtb,
                                                       const float* __restrict__ off,
                                                       float* __restrict__ out) {
    __shared__ unsigned short As[3][256 * 64];   // 96 KB (triple buffer)
    __shared__ unsigned short Bs[2][64 * 64];    // 16 KB

    const int tid  = threadIdx.x;
    const int wv   = tid >> 6;                // 0..7  (M position, 32 rows each)
    const int lane = tid & 63;
    const int quad = lane >> 4;
    const int l15  = lane & 15;

    const int hw_local = tid >> 3;            // 0..63
    const int seg      = tid & 7;             // 8-channel segment within 64

    // XCD-aware decode (gfx950 dispatch: consecutive ids round-robin XCDs)
    const int id  = blockIdx.x;
    const int n   = ((id & 7) << 1) | ((id >> 3) & 1);
    const int hw0 = (id >> 4) * 64;

    const int hw = hw0 + hw_local;
    const int h  = hw >> 5, w = hw & 31;

    // A staging lane pattern (XOR swizzle encoded in source address)
    const int srow   = lane >> 3;
    const int schunk = (lane & 7) ^ (srow & 7);

    const uint4*  xb4  = (const uint4*)(xtb + (size_t)n * HW * CIN);
    const float2* offp = (const float2*)(off + ((size_t)n * HW + hw) * (2 * KK));

    f32x4 acc[2][4] = {};

    auto setup2 = [&](float2 o, int tapv, float* wg, int* ix) {
        float py = (float)(h + tapv / 3 - 1) + o.x;
        float px = (float)(w + tapv % 3 - 1) + o.y;
        float y0f = floorf(py), x0f = floorf(px);
        float ly = py - y0f, lx = px - x0f;
        int y0 = (int)y0f, x0 = (int)x0f;
#pragma unroll
        for (int c2 = 0; c2 < 4; ++c2) {
            int yy = y0 + (c2 >> 1);
            int xx = x0 + (c2 & 1);
            float wy = (c2 >> 1) ? ly : 1.0f - ly;
            float wx = (c2 & 1) ? lx : 1.0f - lx;
            bool v = (yy >= 0) && (yy < HH) && (xx >= 0) && (xx < WW);
            wg[c2] = v ? wy * wx : 0.0f;
            int yc = yy < 0 ? 0 : (yy > HH - 1 ? HH - 1 : yy);
            int xc = xx < 0 ? 0 : (xx > WW - 1 ? WW - 1 : xx);
            ix[c2] = yc * WW + xc;
        }
    };

    auto loadc = [&](uint4 cr[4], const int* ix, int q) {
#pragma unroll
        for (int c2 = 0; c2 < 4; ++c2)
            cr[c2] = xb4[(size_t)ix[c2] * 32 + q * 8 + seg];
    };

    // DMA one 256x64 A tile (kblock kblk) into As[ai]
    auto dmaA = [&](int ai, int kblk) {
        const unsigned short* wsrc = wbf + (size_t)kblk * 64 + (size_t)srow * CK + schunk * 8;
        unsigned short* dst = &As[ai][0];
#pragma unroll
        for (int j = 0; j < 4; ++j) {
            int rb = wv * 32 + j * 8;
            async16(wsrc + (size_t)rb * CK, dst + rb * 64);
        }
    };

    auto lerpB = [&](int bi, const uint4 cr[4], const float* wg) {
        unsigned u0[4], u1[4], u2[4], u3[4];
        *(uint4*)u0 = cr[0]; *(uint4*)u1 = cr[1];
        *(uint4*)u2 = cr[2]; *(uint4*)u3 = cr[3];
        unsigned dw[4];
#pragma unroll
        for (int d = 0; d < 4; ++d) {
            float lo = wg[0] * bflo(u0[d]) + wg[1] * bflo(u1[d])
                     + wg[2] * bflo(u2[d]) + wg[3] * bflo(u3[d]);
            float hi = wg[0] * bfhi(u0[d]) + wg[1] * bfhi(u1[d])
                     + wg[2] * bfhi(u2[d]) + wg[3] * bfhi(u3[d]);
            dw[d] = (unsigned)f2bf(lo) | ((unsigned)f2bf(hi) << 16);
        }
        *(uint4*)&Bs[bi][hw_local * 64 + (seg ^ (hw_local & 7)) * 8] = *(uint4*)dw;
    };

    auto mfma_step = [&](int ai, int bi) {
        const unsigned short* Ap = &As[ai][0];
        const unsigned short* Bp = &Bs[bi][0];
        bf16x8 af[2][2], bfr[4][2];
#pragma unroll
        for (int mi = 0; mi < 2; ++mi)
#pragma unroll
            for (int hh = 0; hh < 2; ++hh) {
                int row = wv * 32 + mi * 16 + l15;
                int ch  = (hh * 4 + quad) ^ (row & 7);
                af[mi][hh] = *(const bf16x8*)(Ap + row * 64 + ch * 8);
            }
#pragma unroll
        for (int ni = 0; ni < 4; ++ni)
#pragma unroll
            for (int hh = 0; hh < 2; ++hh) {
                int row = ni * 16 + l15;
                int ch  = (hh * 4 + quad) ^ (row & 7);
                bfr[ni][hh] = *(const bf16x8*)(Bp + row * 64 + ch * 8);
            }
        __builtin_amdgcn_s_setprio(1);
#pragma unroll
        for (int mi = 0; mi < 2; ++mi)
#pragma unroll
            for (int ni = 0; ni < 4; ++ni) {
                acc[mi][ni] = __builtin_amdgcn_mfma_f32_16x16x32_bf16(af[mi][0], bfr[ni][0], acc[mi][ni], 0, 0, 0);
                acc[mi][ni] = __builtin_amdgcn_mfma_f32_16x16x32_bf16(af[mi][1], bfr[ni][1], acc[mi][ni], 0, 0, 0);
            }
        __builtin_amdgcn_s_setprio(0);
    };

    // ---- prologue: As[0]<-k0, As[1]<-k1 (DMA), Bs[0]<-lerp(k0), crB holds k1
    float wgc[4], wgn[4];
    int   ixc[4], ixn[4];
    uint4 crA[4], crB[4];
    {
        float2 o0 = offp[0];
        setup2(o0, 0, wgc, ixc);
        dmaA(0, 0);
        dmaA(1, 1);
        SB();
        loadc(crA, ixc, 0);
        loadc(crB, ixc, 1);
        SB();
        lerpB(0, crA, wgc);   // compiler wait on crA drains both DMAs (FIFO)
        SYNC();
    }

    // ---- main loop: step s = tap*4+q. mfma reads As[s%3], Bs[s%2].
    // DMA at step s targets As[(s+2)%3] with kblock s+2.
    int i0 = 0;                               // == (tap*4) % 3
#pragma unroll 1
    for (int tap = 0; tap < 9; ++tap) {
        const int i1 = (i0 == 2) ? 0 : i0 + 1;
        const int i2 = (i1 == 2) ? 0 : i1 + 1;
        const int kb = tap * 4;
        const bool more = (tap < 8);

        // q0: dma k(kb+2)->As[i2] | lerp k(kb+1)->Bs[1] | loadc k(kb+2) | mfma k(kb)
        dmaA(i2, kb + 2);
        SB();
        lerpB(1, crB, wgc);
        SB();
        loadc(crA, ixc, 2);
        SB();
        mfma_step(i0, 0);
        SYNC();

        // q1: dma k(kb+3)->As[i0] | lerp k(kb+2)->Bs[0] | loadc k(kb+3) | mfma k(kb+1)
        dmaA(i0, kb + 3);
        SB();
        lerpB(0, crA, wgc);
        SB();
        loadc(crB, ixc, 3);
        SB();
        mfma_step(i1, 1);
        SYNC();

        // q2: offp prefetch FIRST (so its wait can't drain the new DMA)
        //     dma k(kb+4)->As[i1] | lerp k(kb+3)->Bs[1] | setup+loadc k(kb+4) | mfma k(kb+2)
        float2 onx = {};
        if (more) onx = offp[tap + 1];
        SB();
        if (more) dmaA(i1, kb + 4);
        SB();
        lerpB(1, crB, wgc);
        SB();
        if (more) { setup2(onx, tap + 1, wgn, ixn); loadc(crA, ixn, 0); }
        SB();
        mfma_step(i2, 0);
        SYNC();

        // q3: dma k(kb+5)->As[i2] | lerp k(kb+4)->Bs[0] (new tap!) | loadc k(kb+5) | mfma k(kb+3)
        if (more) {
            dmaA(i2, kb + 5);
            SB();
            lerpB(0, crA, wgn);
            SB();
            loadc(crB, ixn, 1);
#pragma unroll
            for (int c2 = 0; c2 < 4; ++c2) { wgc[c2] = wgn[c2]; ixc[c2] = ixn[c2]; }
            SB();
            mfma_step(i0, 1);
            SYNC();
        } else {
            mfma_step(i0, 1);        // last step, no barrier needed after
        }
        i0 = i1;
    }

    // ---- epilogue: D layout col = lane&15, row = quad*4 + reg
    float* opnt = out + (size_t)n * COUT * HW + hw0;
#pragma unroll
    for (int mi = 0; mi < 2; ++mi)
#pragma unroll
        for (int ni = 0; ni < 4; ++ni) {
            int col = ni * 16 + l15;
#pragma unroll
            for (int rr = 0; rr < 4; ++rr) {
                int row = wv * 32 + mi * 16 + quad * 4 + rr;
                opnt[(size_t)row * HW + col] = acc[mi][ni][rr];
            }
        }
}

// --------------------------------------------------------------- launch ----
extern "C" void kernel_launch(void* const* d_in, const int* in_sizes, int n_in,
                              void* d_out, int out_size, void* d_ws, size_t ws_size,
                              hipStream_t stream) {
    const float* x   = (const float*)d_in[0];   // [16][256][32][32]
    const float* off = (const float*)d_in[1];   // [16][1024][18]
    const float* wt  = (const float*)d_in[2];   // [256][256][3][3]
    float* out = (float*)d_out;                 // [16][256][32][32]

    unsigned short* wbf = (unsigned short*)d_ws;                        // 1179648 B
    unsigned short* xtb = (unsigned short*)((char*)d_ws + 1179648);     // 8388608 B

    prep_kernel<<<1280, 256, 0, stream>>>(wt, wbf, x, xtb);
    fused_kernel<<<256, 512, 0, stream>>>(wbf, xtb, off, out);
}

// Round 6
// 112.743 us; speedup vs baseline: 1.8874x; 1.0597x over previous
//
#include <hip/hip_runtime.h>

// Problem constants
#define NB   16
#define CIN  256
#define COUT 256
#define HH   32
#define WW   32
#define HW   1024           // 32*32
#define KK   9
#define CK   2304           // CIN*KK  (ordered k*256 + c, tap-major)

typedef __bf16 bf16x8 __attribute__((ext_vector_type(8)));
typedef float  f32x4  __attribute__((ext_vector_type(4)));

__device__ __forceinline__ unsigned short f2bf(float f) {
    unsigned int u = __float_as_uint(f);
    u += 0x7FFFu + ((u >> 16) & 1u);          // round-nearest-even
    return (unsigned short)(u >> 16);
}
__device__ __forceinline__ float bfhi(unsigned int u) {   // high bf16 -> f32
    return __uint_as_float(u & 0xFFFF0000u);
}
__device__ __forceinline__ float bflo(unsigned int u) {   // low bf16 -> f32
    return __uint_as_float(u << 16);
}
// pack two f32 -> one dword of 2x bf16 (RNE). No builtin on gfx950 (ROCm 7.2)
// — inline asm v_cvt_pk_bf16_f32: src0 -> low 16, src1 -> high 16.
__device__ __forceinline__ unsigned pk2(float lo, float hi) {
    unsigned r;
    asm("v_cvt_pk_bf16_f32 %0, %1, %2" : "=v"(r) : "v"(lo), "v"(hi));
    return r;
}

typedef const __attribute__((address_space(1))) void* gas_ptr;
typedef __attribute__((address_space(3))) void* las_ptr;

__device__ __forceinline__ void async16(const void* g, void* l) {
    __builtin_amdgcn_global_load_lds((gas_ptr)g, (las_ptr)l, 16, 0, 0);
}

#define SB() __builtin_amdgcn_sched_barrier(0)
// Raw barrier: LDS-visibility only. vmcnt is deliberately NOT drained —
// A-DMA completion is enforced by vmcnt FIFO order (the lerp's wait on the
// younger corner-gather loads implies the older DMAs are done).
#define SYNC() do { SB(); asm volatile("s_waitcnt lgkmcnt(0)" ::: "memory"); SB(); \
                    __builtin_amdgcn_s_barrier(); SB(); } while (0)

// ----------------------------------------------------------------- prep ----
// One kernel, two roles (saves a launch and runs them concurrently):
//   blocks [0,256):    weight fp32 [O][C][3][3] -> bf16 [O][k*256+c]
//   blocks [256,1280): x fp32 [n][c][hw] -> xtb bf16 [n][hw][c] (64x64 tiles)
// Grid-barrier mono fusion measured WORSE (round 3: agent-fence L2
// invalidation costs ~100 us of gather latency) — keep two dispatches.
__global__ __launch_bounds__(256) void prep_kernel(const float* __restrict__ w,
                                                   unsigned short* __restrict__ wbf,
                                                   const float* __restrict__ x,
                                                   unsigned short* __restrict__ xtb) {
    __shared__ float lsbuf[64 * 65];
    const int t = threadIdx.x;

    if (blockIdx.x < 256) {
        // ---- wconv role
        const int o = blockIdx.x;
        const float* wo = w + (size_t)o * CK;
#pragma unroll
        for (int i = t; i < CK; i += 256) lsbuf[i] = wo[i];
        __syncthreads();
        unsigned short* dst = wbf + (size_t)o * CK;
#pragma unroll
        for (int i = t; i < CK; i += 256) {
            int k = i >> 8, c = i & 255;
            dst[i] = f2bf(lsbuf[c * KK + k]);     // bank stride 9: conflict-free
        }
        return;
    }

    // ---- xt role
    float (*ls)[65] = (float(*)[65])lsbuf;
    const int id  = blockIdx.x - 256;
    const int c0  = (id & 3) << 6;
    const int hw0 = ((id >> 2) & 15) << 6;
    const int n   = id >> 6;
    {
        int c = t >> 2, q = t & 3;
        const float4* base = (const float4*)(x + ((size_t)(n * CIN + c0 + c)) * HW + hw0 + q * 16);
#pragma unroll
        for (int j = 0; j < 4; ++j) {
            float4 v = base[j];
            ls[c][q * 16 + j * 4 + 0] = v.x;
            ls[c][q * 16 + j * 4 + 1] = v.y;
            ls[c][q * 16 + j * 4 + 2] = v.z;
            ls[c][q * 16 + j * 4 + 3] = v.w;
        }
    }
    __syncthreads();
    {
        int hw = t >> 2, seg = (t & 3) * 16;
        unsigned int dw[8];
#pragma unroll
        for (int j = 0; j < 8; ++j) {
            float f0 = ls[seg + 2 * j][hw];
            float f1 = ls[seg + 2 * j + 1][hw];
            dw[j] = (unsigned)f2bf(f0) | ((unsigned)f2bf(f1) << 16);
        }
        uint4* dst = (uint4*)(xtb + ((size_t)(n * HW + hw0 + hw)) * CIN + c0 + seg);
        dst[0] = *(uint4*)&dw[0];
        dst[1] = *(uint4*)&dw[4];
    }
}

// ---------------------------------------------------------------- fused ----
// BM=256, BN=64, BK=64, 512 thr / 8 waves, wave tile 32(o) x 64(hw).
// As triple-buffered (DMA 2 steps ahead; completion via vmcnt FIFO order —
// never drained at barriers); Bs double-buffered, lerped one step ahead
// from prefetched corner regs. Raw barrier (lgkmcnt(0)+s_barrier).
//
// Step-internal phase order (round-5/6 change): frag ds_reads are issued
// FIRST after the barrier (buffers were filled last step, so they only
// depend on the barrier); DMA-issue / lerp-VALU / gather-issue run under
// the read shadow; the MFMA cluster runs last with compiler-placed
// lgkmcnt waits. This de-lockstops the LDS port and the VALU across the
// CU's 8 waves (previous order serialized phases: all-VALU then all-LDS).
__global__ __launch_bounds__(512, 2) void fused_kernel(const unsigned short* __restrict__ wbf,
                                                       const unsigned short* __restrict__ xtb,
                                                       const float* __restrict__ off,
                                                       float* __restrict__ out) {
    __shared__ unsigned short As[3][256 * 64];   // 96 KB (triple buffer)
    __shared__ unsigned short Bs[2][64 * 64];    // 16 KB

    const int tid  = threadIdx.x;
    const int wv   = tid >> 6;                // 0..7  (M position, 32 rows each)
    const int lane = tid & 63;
    const int quad = lane >> 4;
    const int l15  = lane & 15;

    const int hw_local = tid >> 3;            // 0..63
    const int seg      = tid & 7;             // 8-channel segment within 64

    // XCD-aware decode (gfx950 dispatch: consecutive ids round-robin XCDs)
    const int id  = blockIdx.x;
    const int n   = ((id & 7) << 1) | ((id >> 3) & 1);
    const int hw0 = (id >> 4) * 64;

    const int hw = hw0 + hw_local;
    const int h  = hw >> 5, w = hw & 31;

    // A staging lane pattern (XOR swizzle encoded in source address)
    const int srow   = lane >> 3;
    const int schunk = (lane & 7) ^ (srow & 7);

    const uint4*  xb4  = (const uint4*)(xtb + (size_t)n * HW * CIN);
    const float2* offp = (const float2*)(off + ((size_t)n * HW + hw) * (2 * KK));

    f32x4 acc[2][4] = {};

    auto setup2 = [&](float2 o, int tapv, float* wg, int* ix) {
        float py = (float)(h + tapv / 3 - 1) + o.x;
        float px = (float)(w + tapv % 3 - 1) + o.y;
        float y0f = floorf(py), x0f = floorf(px);
        float ly = py - y0f, lx = px - x0f;
        int y0 = (int)y0f, x0 = (int)x0f;
#pragma unroll
        for (int c2 = 0; c2 < 4; ++c2) {
            int yy = y0 + (c2 >> 1);
            int xx = x0 + (c2 & 1);
            float wy = (c2 >> 1) ? ly : 1.0f - ly;
            float wx = (c2 & 1) ? lx : 1.0f - lx;
            bool v = (yy >= 0) && (yy < HH) && (xx >= 0) && (xx < WW);
            wg[c2] = v ? wy * wx : 0.0f;
            int yc = yy < 0 ? 0 : (yy > HH - 1 ? HH - 1 : yy);
            int xc = xx < 0 ? 0 : (xx > WW - 1 ? WW - 1 : xx);
            ix[c2] = yc * WW + xc;
        }
    };

    auto loadc = [&](uint4 cr[4], const int* ix, int q) {
#pragma unroll
        for (int c2 = 0; c2 < 4; ++c2)
            cr[c2] = xb4[(size_t)ix[c2] * 32 + q * 8 + seg];
    };

    // DMA one 256x64 A tile (kblock kblk) into As[ai]
    auto dmaA = [&](int ai, int kblk) {
        const unsigned short* wsrc = wbf + (size_t)kblk * 64 + (size_t)srow * CK + schunk * 8;
        unsigned short* dst = &As[ai][0];
#pragma unroll
        for (int j = 0; j < 4; ++j) {
            int rb = wv * 32 + j * 8;
            async16(wsrc + (size_t)rb * CK, dst + rb * 64);
        }
    };

    auto lerpB = [&](int bi, const uint4 cr[4], const float* wg) {
        unsigned u0[4], u1[4], u2[4], u3[4];
        *(uint4*)u0 = cr[0]; *(uint4*)u1 = cr[1];
        *(uint4*)u2 = cr[2]; *(uint4*)u3 = cr[3];
        unsigned dw[4];
#pragma unroll
        for (int d = 0; d < 4; ++d) {
            float lo = wg[0] * bflo(u0[d]) + wg[1] * bflo(u1[d])
                     + wg[2] * bflo(u2[d]) + wg[3] * bflo(u3[d]);
            float hi = wg[0] * bfhi(u0[d]) + wg[1] * bfhi(u1[d])
                     + wg[2] * bfhi(u2[d]) + wg[3] * bfhi(u3[d]);
            dw[d] = pk2(lo, hi);              // v_cvt_pk_bf16_f32 (RNE)
        }
        *(uint4*)&Bs[bi][hw_local * 64 + (seg ^ (hw_local & 7)) * 8] = *(uint4*)dw;
    };

    // issue the 12 frag ds_reads (no waits here; compiler places lgkmcnt
    // right before the MFMA uses)
    auto frag_read = [&](int ai, int bi, bf16x8 af[2][2], bf16x8 bfr[4][2]) {
        const unsigned short* Ap = &As[ai][0];
        const unsigned short* Bp = &Bs[bi][0];
#pragma unroll
        for (int mi = 0; mi < 2; ++mi)
#pragma unroll
            for (int hh = 0; hh < 2; ++hh) {
                int row = wv * 32 + mi * 16 + l15;
                int ch  = (hh * 4 + quad) ^ (row & 7);
                af[mi][hh] = *(const bf16x8*)(Ap + row * 64 + ch * 8);
            }
#pragma unroll
        for (int ni = 0; ni < 4; ++ni)
#pragma unroll
            for (int hh = 0; hh < 2; ++hh) {
                int row = ni * 16 + l15;
                int ch  = (hh * 4 + quad) ^ (row & 7);
                bfr[ni][hh] = *(const bf16x8*)(Bp + row * 64 + ch * 8);
            }
    };

    auto frag_mma = [&](bf16x8 af[2][2], bf16x8 bfr[4][2]) {
        __builtin_amdgcn_s_setprio(1);
#pragma unroll
        for (int mi = 0; mi < 2; ++mi)
#pragma unroll
            for (int ni = 0; ni < 4; ++ni) {
                acc[mi][ni] = __builtin_amdgcn_mfma_f32_16x16x32_bf16(af[mi][0], bfr[ni][0], acc[mi][ni], 0, 0, 0);
                acc[mi][ni] = __builtin_amdgcn_mfma_f32_16x16x32_bf16(af[mi][1], bfr[ni][1], acc[mi][ni], 0, 0, 0);
            }
        __builtin_amdgcn_s_setprio(0);
    };

    // ---- prologue: As[0]<-k0, As[1]<-k1 (DMA), Bs[0]<-lerp(k0), crB holds k1
    float wgc[4], wgn[4];
    int   ixc[4], ixn[4];
    uint4 crA[4], crB[4];
    {
        float2 o0 = offp[0];
        setup2(o0, 0, wgc, ixc);
        dmaA(0, 0);
        dmaA(1, 1);
        SB();
        loadc(crA, ixc, 0);
        loadc(crB, ixc, 1);
        SB();
        lerpB(0, crA, wgc);   // compiler wait on crA drains both DMAs (FIFO)
        SYNC();
    }

    // ---- main loop: step s = tap*4+q. mfma reads As[s%3], Bs[s%2].
    // DMA at step s targets As[(s+2)%3] with kblock s+2.
    int i0 = 0;                               // == (tap*4) % 3
#pragma unroll 1
    for (int tap = 0; tap < 9; ++tap) {
        const int i1 = (i0 == 2) ? 0 : i0 + 1;
        const int i2 = (i1 == 2) ? 0 : i1 + 1;
        const int kb = tap * 4;
        const bool more = (tap < 8);
        bf16x8 af[2][2], bfr[4][2];

        // q0: reads(i0,B0) | dma k(kb+2)->As[i2] | lerp k(kb+1)->Bs[1]
        //     | loadc k(kb+2) | mfma
        frag_read(i0, 0, af, bfr);
        SB();
        dmaA(i2, kb + 2);
        SB();
        lerpB(1, crB, wgc);
        SB();
        loadc(crA, ixc, 2);
        SB();
        frag_mma(af, bfr);
        SYNC();

        // q1: reads(i1,B1) | dma k(kb+3)->As[i0] | lerp k(kb+2)->Bs[0]
        //     | loadc k(kb+3) | mfma
        frag_read(i1, 1, af, bfr);
        SB();
        dmaA(i0, kb + 3);
        SB();
        lerpB(0, crA, wgc);
        SB();
        loadc(crB, ixc, 3);
        SB();
        frag_mma(af, bfr);
        SYNC();

        // q2: offp prefetch FIRST (so its wait can't drain the new DMA)
        //     reads(i2,B0) | dma k(kb+4)->As[i1] | lerp k(kb+3)->Bs[1]
        //     | setup+loadc k(kb+4) | mfma
        float2 onx = {};
        if (more) onx = offp[tap + 1];
        SB();
        frag_read(i2, 0, af, bfr);
        SB();
        if (more) dmaA(i1, kb + 4);
        SB();
        lerpB(1, crB, wgc);
        SB();
        if (more) { setup2(onx, tap + 1, wgn, ixn); loadc(crA, ixn, 0); }
        SB();
        frag_mma(af, bfr);
        SYNC();

        // q3: reads(i0,B1) | dma k(kb+5)->As[i2] | lerp k(kb+4)->Bs[0]
        //     (new tap!) | loadc k(kb+5) | mfma
        frag_read(i0, 1, af, bfr);
        SB();
        if (more) {
            dmaA(i2, kb + 5);
            SB();
            lerpB(0, crA, wgn);
            SB();
            loadc(crB, ixn, 1);
#pragma unroll
            for (int c2 = 0; c2 < 4; ++c2) { wgc[c2] = wgn[c2]; ixc[c2] = ixn[c2]; }
            SB();
            frag_mma(af, bfr);
            SYNC();
        } else {
            frag_mma(af, bfr);       // last step, no barrier needed after
        }
        i0 = i1;
    }

    // ---- epilogue: D layout col = lane&15, row = quad*4 + reg
    float* opnt = out + (size_t)n * COUT * HW + hw0;
#pragma unroll
    for (int mi = 0; mi < 2; ++mi)
#pragma unroll
        for (int ni = 0; ni < 4; ++ni) {
            int col = ni * 16 + l15;
#pragma unroll
            for (int rr = 0; rr < 4; ++rr) {
                int row = wv * 32 + mi * 16 + quad * 4 + rr;
                opnt[(size_t)row * HW + col] = acc[mi][ni][rr];
            }
        }
}

// --------------------------------------------------------------- launch ----
extern "C" void kernel_launch(void* const* d_in, const int* in_sizes, int n_in,
                              void* d_out, int out_size, void* d_ws, size_t ws_size,
                              hipStream_t stream) {
    const float* x   = (const float*)d_in[0];   // [16][256][32][32]
    const float* off = (const float*)d_in[1];   // [16][1024][18]
    const float* wt  = (const float*)d_in[2];   // [256][256][3][3]
    float* out = (float*)d_out;                 // [16][256][32][32]

    unsigned short* wbf = (unsigned short*)d_ws;                        // 1179648 B
    unsigned short* xtb = (unsigned short*)((char*)d_ws + 1179648);     // 8388608 B

    prep_kernel<<<1280, 256, 0, stream>>>(wt, wbf, x, xtb);
    fused_kernel<<<256, 512, 0, stream>>>(wbf, xtb, off, out);
}